// Round 13
// baseline (214.537 us; speedup 1.0000x reference)
//
#include <hip/hip_runtime.h>
#include <math.h>

// (N,C,H,W) = (4,19,512,1024), f32 input, scalar f32 output.
// R13 = DIAGNOSTIC on R12 structure: tile pipeline repeated DIAG_REPS=5x
// in-kernel (flush /5) so pass1 (~125us) finally outranks the ~90us harness
// poison-fills in the profile top-5 -> first-ever pass1 counters
// (VALUBusy/Occupancy/FETCH/timestamps). Decision tree in journal.
#define NC 19
#define NN 4
#define HH 512
#define WW 1024
#define NBLK 512             // 512 blocks * 256 thr * 8 tiles * 2 px = Np
#define TILES 8
#define NREP 32              // LDS accumulator replicas (rep = tid & 31)
#define COLS (2 * NC)        // 19 ssum cols + 19 hist cols
#define CSTRIDE 512          // column stride in ws (== NBLK)
#define DIAG_REPS 5

typedef float floatx2 __attribute__((ext_vector_type(2)));

__global__ __launch_bounds__(256) void msiw_pass1(const float* __restrict__ x,
                                                  float* __restrict__ ws) {
    __shared__ float s_acc[2][NREP][NC];   // [0]=ssum, [1]=count (float, exact)
    const int tid = threadIdx.x;

    for (int i = tid; i < 2 * NREP * NC; i += 256) (&s_acc[0][0][0])[i] = 0.0f;
    __syncthreads();

    const size_t cs = (size_t)HH * WW;     // channel stride (elements)
    const int rep = tid & (NREP - 1);      // <=2-way same-address alias (free)

    float buf[2][NC][2];

    #define TILE_BASE(r) ({                                                   \
        const int u    = (blockIdx.x * TILES + (r)) * 256 + tid;              \
        const int w2   = u & 511;              /* W/2 = 512 */                \
        const int rest = u >> 9;                                              \
        const int h    = rest & 511;                                          \
        const int n    = rest >> 9;                                           \
        ((size_t)(n * NC) * HH + h) * WW + (size_t)w2 * 2; })

    #define LOAD_TILE(r, B)                                                   \
        {                                                                     \
            const size_t base_ = TILE_BASE(r);                                \
            _Pragma("unroll")                                                 \
            for (int c = 0; c < NC; ++c) {                                    \
                const floatx2* p2 = reinterpret_cast<const floatx2*>(         \
                    x + base_ + (size_t)c * cs);                              \
                const floatx2 v = __builtin_nontemporal_load(p2);             \
                buf[B][c][0] = v.x; buf[B][c][1] = v.y;                       \
            }                                                                 \
        }

    #define COMPUTE_TILE(B)                                                   \
        {                                                                     \
            float Z0 = 0.f, Z1 = 0.f, Q0 = 0.f, Q1 = 0.f;                     \
            float m0 = buf[B][0][0], m1 = buf[B][0][1];                       \
            int   p0 = 0, p1 = 0;                                             \
            _Pragma("unroll")                                                 \
            for (int c = 0; c < NC; ++c) {                                    \
                const float x0 = buf[B][c][0], x1 = buf[B][c][1];             \
                const float e0 = __expf(x0), e1 = __expf(x1);                 \
                Z0 += e0; Z1 += e1;                                           \
                Q0 = fmaf(e0, e0, Q0); Q1 = fmaf(e1, e1, Q1);                 \
                if (c > 0) {                                                  \
                    if (x0 > m0) { m0 = x0; p0 = c; }                         \
                    if (x1 > m1) { m1 = x1; p1 = c; }                         \
                }                                                             \
            }                                                                 \
            atomicAdd(&s_acc[0][rep][p0], Q0 / (Z0 * Z0));                    \
            atomicAdd(&s_acc[1][rep][p0], 1.0f);                              \
            atomicAdd(&s_acc[0][rep][p1], Q1 / (Z1 * Z1));                    \
            atomicAdd(&s_acc[1][rep][p1], 1.0f);                              \
        }

    #pragma unroll 1
    for (int dr = 0; dr < DIAG_REPS; ++dr) {
        // Software pipeline: load r+1 while computing r (static buffer idx).
        LOAD_TILE(0, 0);
        asm volatile("" ::: "memory");
        #pragma unroll
        for (int r = 0; r < TILES - 1; ++r) {
            LOAD_TILE(r + 1, (r + 1) & 1);
            asm volatile("" ::: "memory");
            COMPUTE_TILE(r & 1);
        }
        COMPUTE_TILE((TILES - 1) & 1);
    }

    __syncthreads();
    // Flush 38 per-block partials (/DIAG_REPS), column-major:
    // ws[col*NBLK + block]. Kernel boundary = device-scope release.
    if (tid < COLS) {
        const int a = (tid < NC) ? 0 : 1;
        const int c = (tid < NC) ? tid : (tid - NC);
        float acc = 0.0f;
        #pragma unroll
        for (int rp = 0; rp < NREP; ++rp) acc += s_acc[a][rp][c];
        ws[(size_t)tid * CSTRIDE + blockIdx.x] = acc / (float)DIAG_REPS;
    }
}

// 16 waves: wave w reduces columns w, w+16, w+32; float4 batched loads.
__global__ __launch_bounds__(1024) void msiw_pass2(const float* __restrict__ ws,
                                                   float* __restrict__ out) {
    __shared__ float s_col[COLS];
    const int tid  = threadIdx.x;
    const int wv   = tid >> 6;       // 0..15
    const int lane = tid & 63;

    for (int col = wv; col < COLS; col += 16) {
        const float4* q = reinterpret_cast<const float4*>(ws + (size_t)col * CSTRIDE);
        float4 a[2];
        #pragma unroll
        for (int i = 0; i < 2; ++i) a[i] = q[lane + i * 64];   // 128 float4 = 512 f
        float acc = 0.0f;
        #pragma unroll
        for (int i = 0; i < 2; ++i) acc += (a[i].x + a[i].y) + (a[i].z + a[i].w);
        #pragma unroll
        for (int off = 32; off > 0; off >>= 1) acc += __shfl_down(acc, off);
        if (lane == 0) s_col[col] = acc;
    }
    __syncthreads();

    if (tid == 0) {
        const double np_pow = pow((double)NN * HH * WW, 0.8);   // Np^(1-iw)
        double total = 0.0;
        for (int c = 0; c < NC; ++c) {
            double den = pow((double)s_col[NC + c], 0.2) * np_pow;
            if (den < 1.0) den = 1.0;
            total += (double)s_col[c] / den;
        }
        out[0] = (float)(-total / (double)(NN * NC));
    }
}

extern "C" void kernel_launch(void* const* d_in, const int* in_sizes, int n_in,
                              void* d_out, int out_size, void* d_ws, size_t ws_size,
                              hipStream_t stream) {
    const float* x = (const float*)d_in[0];
    float* ws = (float*)d_ws;                 // 38 cols * 512 floats = 78 KB
    float* out = (float*)d_out;

    msiw_pass1<<<NBLK, 256, 0, stream>>>(x, ws);
    msiw_pass2<<<1, 1024, 0, stream>>>(ws, out);
}

// Round 14
// 48.909 us; speedup vs baseline: 4.3865x; 4.3865x over previous
//
#include <hip/hip_runtime.h>
#include <math.h>

// (N,C,H,W) = (4,19,512,1024), f32 input, scalar f32 output.
// R14 change (single variable vs R12): load width float2 -> float4.
// R13 diag found the per-CU outstanding-request queue is INSTRUCTION-
// granular (R9 float4 marginal 21us/rep vs R13 float2 marginal 42us/rep,
// exactly 2x) -> wider loads = more bytes in flight per queue slot.
// 512 blocks x 256 thr x 4 tiles x 4 px (float4) = Np. Double-buffered
// register pipeline kept from R11/R12. VGPR stays in the 129-256 band
// (8 waves/CU) so the width effect is isolated.
#define NC 19
#define NN 4
#define HH 512
#define WW 1024
#define NBLK 512             // 512 * 256 * 4 tiles * 4 px = Np
#define TILES 4
#define NREP 32              // LDS accumulator replicas (rep = tid & 31)
#define COLS (2 * NC)        // 19 ssum cols + 19 hist cols
#define CSTRIDE 512          // column stride in ws (== NBLK)

typedef float floatx4 __attribute__((ext_vector_type(4)));

__global__ __launch_bounds__(256) void msiw_pass1(const float* __restrict__ x,
                                                  float* __restrict__ ws) {
    __shared__ float s_acc[2][NREP][NC];   // [0]=ssum, [1]=count (float, exact)
    const int tid = threadIdx.x;

    for (int i = tid; i < 2 * NREP * NC; i += 256) (&s_acc[0][0][0])[i] = 0.0f;
    __syncthreads();

    const size_t cs = (size_t)HH * WW;     // channel stride (elements)
    const int rep = tid & (NREP - 1);      // <=2-way same-address alias (free)

    float buf[2][NC][4];

    #define TILE_BASE(r) ({                                                   \
        const int u    = (blockIdx.x * TILES + (r)) * 256 + tid;              \
        const int w4   = u & 255;              /* W/4 = 256 */                \
        const int rest = u >> 8;                                              \
        const int h    = rest & 511;                                          \
        const int n    = rest >> 9;                                           \
        ((size_t)(n * NC) * HH + h) * WW + (size_t)w4 * 4; })

    #define LOAD_TILE(r, B)                                                   \
        {                                                                     \
            const size_t base_ = TILE_BASE(r);                                \
            _Pragma("unroll")                                                 \
            for (int c = 0; c < NC; ++c) {                                    \
                const floatx4* p4 = reinterpret_cast<const floatx4*>(         \
                    x + base_ + (size_t)c * cs);                              \
                const floatx4 v = *p4;      /* global_load_dwordx4 */         \
                buf[B][c][0] = v.x; buf[B][c][1] = v.y;                       \
                buf[B][c][2] = v.z; buf[B][c][3] = v.w;                       \
            }                                                                 \
        }

    #define COMPUTE_TILE(B)                                                   \
        {                                                                     \
            float Z[4] = {0.f, 0.f, 0.f, 0.f};                                \
            float Q[4] = {0.f, 0.f, 0.f, 0.f};                                \
            float m[4]; int p[4];                                             \
            _Pragma("unroll")                                                 \
            for (int k = 0; k < 4; ++k) { m[k] = buf[B][0][k]; p[k] = 0; }    \
            _Pragma("unroll")                                                 \
            for (int c = 0; c < NC; ++c) {                                    \
                _Pragma("unroll")                                             \
                for (int k = 0; k < 4; ++k) {                                 \
                    const float xv = buf[B][c][k];                            \
                    const float e  = __expf(xv);                              \
                    Z[k] += e;                                                \
                    Q[k] = fmaf(e, e, Q[k]);                                  \
                    if (c > 0 && xv > m[k]) { m[k] = xv; p[k] = c; }          \
                }                                                             \
            }                                                                 \
            _Pragma("unroll")                                                 \
            for (int k = 0; k < 4; ++k) {                                     \
                atomicAdd(&s_acc[0][rep][p[k]], Q[k] / (Z[k] * Z[k]));        \
                atomicAdd(&s_acc[1][rep][p[k]], 1.0f);                        \
            }                                                                 \
        }

    // Software pipeline: load r+1 while computing r (static buffer indices).
    LOAD_TILE(0, 0);
    asm volatile("" ::: "memory");
    #pragma unroll
    for (int r = 0; r < TILES - 1; ++r) {
        LOAD_TILE(r + 1, (r + 1) & 1);
        asm volatile("" ::: "memory");
        COMPUTE_TILE(r & 1);
    }
    COMPUTE_TILE((TILES - 1) & 1);

    __syncthreads();
    // Flush 38 per-block partials, column-major: ws[col*NBLK + block].
    // Kernel boundary provides the device-scope release (no fence needed).
    if (tid < COLS) {
        const int a = (tid < NC) ? 0 : 1;
        const int c = (tid < NC) ? tid : (tid - NC);
        float acc = 0.0f;
        #pragma unroll
        for (int rp = 0; rp < NREP; ++rp) acc += s_acc[a][rp][c];
        ws[(size_t)tid * CSTRIDE + blockIdx.x] = acc;
    }
}

// 16 waves: wave w reduces columns w, w+16, w+32; float4 batched loads.
__global__ __launch_bounds__(1024) void msiw_pass2(const float* __restrict__ ws,
                                                   float* __restrict__ out) {
    __shared__ float s_col[COLS];
    const int tid  = threadIdx.x;
    const int wv   = tid >> 6;       // 0..15
    const int lane = tid & 63;

    for (int col = wv; col < COLS; col += 16) {
        const float4* q = reinterpret_cast<const float4*>(ws + (size_t)col * CSTRIDE);
        float4 a[2];
        #pragma unroll
        for (int i = 0; i < 2; ++i) a[i] = q[lane + i * 64];   // 128 float4 = 512 f
        float acc = 0.0f;
        #pragma unroll
        for (int i = 0; i < 2; ++i) acc += (a[i].x + a[i].y) + (a[i].z + a[i].w);
        #pragma unroll
        for (int off = 32; off > 0; off >>= 1) acc += __shfl_down(acc, off);
        if (lane == 0) s_col[col] = acc;
    }
    __syncthreads();

    if (tid == 0) {
        const double np_pow = pow((double)NN * HH * WW, 0.8);   // Np^(1-iw)
        double total = 0.0;
        for (int c = 0; c < NC; ++c) {
            double den = pow((double)s_col[NC + c], 0.2) * np_pow;
            if (den < 1.0) den = 1.0;
            total += (double)s_col[c] / den;
        }
        out[0] = (float)(-total / (double)(NN * NC));
    }
}

extern "C" void kernel_launch(void* const* d_in, const int* in_sizes, int n_in,
                              void* d_out, int out_size, void* d_ws, size_t ws_size,
                              hipStream_t stream) {
    const float* x = (const float*)d_in[0];
    float* ws = (float*)d_ws;                 // 38 cols * 512 floats = 78 KB
    float* out = (float*)d_out;

    msiw_pass1<<<NBLK, 256, 0, stream>>>(x, ws);
    msiw_pass2<<<1, 1024, 0, stream>>>(ws, out);
}

// Round 15
// 46.726 us; speedup vs baseline: 4.5914x; 1.0467x over previous
//
#include <hip/hip_runtime.h>
#include <math.h>

// (N,C,H,W) = (4,19,512,1024), f32 input, scalar f32 output.
// R15 change vs R12/R11: RAISE RESIDENT WAVES. Ledger model: stream BW
// scales with waves/CU issuing loads (R9 marginal 21us @~16 waves/CU vs
// R13 marginal 42us @8 waves/CU; R14 float4 @8 waves didn't help ->
// occupancy, not load width, is the lever).
//   - 1024 blocks (4/CU) so the grid supplies 16 waves/CU
//   - __launch_bounds__(256, 4) forces VGPR <= 128 -> 4 waves/SIMD
//   - float2 double-buffered 2-deep pipeline kept from R11/R12
#define NC 19
#define NN 4
#define HH 512
#define WW 1024
#define NBLK 1024            // 1024 blocks * 256 thr * 4 tiles * 2 px = Np
#define TILES 4
#define NREP 32              // LDS accumulator replicas (rep = tid & 31)
#define COLS (2 * NC)        // 19 ssum cols + 19 hist cols
#define CSTRIDE 1024         // column stride in ws (== NBLK)

typedef float floatx2 __attribute__((ext_vector_type(2)));

__global__ __launch_bounds__(256, 4) void msiw_pass1(const float* __restrict__ x,
                                                     float* __restrict__ ws) {
    __shared__ float s_acc[2][NREP][NC];   // [0]=ssum, [1]=count (float, exact)
    const int tid = threadIdx.x;

    for (int i = tid; i < 2 * NREP * NC; i += 256) (&s_acc[0][0][0])[i] = 0.0f;
    __syncthreads();

    const size_t cs = (size_t)HH * WW;     // channel stride (elements)
    const int rep = tid & (NREP - 1);      // <=2-way same-address alias (free)

    float buf[2][NC][2];

    #define TILE_BASE(r) ({                                                   \
        const int u    = (blockIdx.x * TILES + (r)) * 256 + tid;              \
        const int w2   = u & 511;              /* W/2 = 512 */                \
        const int rest = u >> 9;                                              \
        const int h    = rest & 511;                                          \
        const int n    = rest >> 9;                                           \
        ((size_t)(n * NC) * HH + h) * WW + (size_t)w2 * 2; })

    #define LOAD_TILE(r, B)                                                   \
        {                                                                     \
            const size_t base_ = TILE_BASE(r);                                \
            _Pragma("unroll")                                                 \
            for (int c = 0; c < NC; ++c) {                                    \
                const floatx2* p2 = reinterpret_cast<const floatx2*>(         \
                    x + base_ + (size_t)c * cs);                              \
                const floatx2 v = *p2;                                        \
                buf[B][c][0] = v.x; buf[B][c][1] = v.y;                       \
            }                                                                 \
        }

    #define COMPUTE_TILE(B)                                                   \
        {                                                                     \
            float Z0 = 0.f, Z1 = 0.f, Q0 = 0.f, Q1 = 0.f;                     \
            float m0 = buf[B][0][0], m1 = buf[B][0][1];                       \
            int   p0 = 0, p1 = 0;                                             \
            _Pragma("unroll")                                                 \
            for (int c = 0; c < NC; ++c) {                                    \
                const float x0 = buf[B][c][0], x1 = buf[B][c][1];             \
                const float e0 = __expf(x0), e1 = __expf(x1);                 \
                Z0 += e0; Z1 += e1;                                           \
                Q0 = fmaf(e0, e0, Q0); Q1 = fmaf(e1, e1, Q1);                 \
                if (c > 0) {                                                  \
                    if (x0 > m0) { m0 = x0; p0 = c; }                         \
                    if (x1 > m1) { m1 = x1; p1 = c; }                         \
                }                                                             \
            }                                                                 \
            atomicAdd(&s_acc[0][rep][p0], Q0 / (Z0 * Z0));                    \
            atomicAdd(&s_acc[1][rep][p0], 1.0f);                              \
            atomicAdd(&s_acc[0][rep][p1], Q1 / (Z1 * Z1));                    \
            atomicAdd(&s_acc[1][rep][p1], 1.0f);                              \
        }

    // Software pipeline: load r+1 while computing r (static buffer indices).
    LOAD_TILE(0, 0);
    asm volatile("" ::: "memory");
    #pragma unroll
    for (int r = 0; r < TILES - 1; ++r) {
        LOAD_TILE(r + 1, (r + 1) & 1);
        asm volatile("" ::: "memory");
        COMPUTE_TILE(r & 1);
    }
    COMPUTE_TILE((TILES - 1) & 1);

    __syncthreads();
    // Flush 38 per-block partials, column-major: ws[col*NBLK + block].
    // Kernel boundary provides the device-scope release (no fence needed).
    if (tid < COLS) {
        const int a = (tid < NC) ? 0 : 1;
        const int c = (tid < NC) ? tid : (tid - NC);
        float acc = 0.0f;
        #pragma unroll
        for (int rp = 0; rp < NREP; ++rp) acc += s_acc[a][rp][c];
        ws[(size_t)tid * CSTRIDE + blockIdx.x] = acc;
    }
}

// 16 waves: wave w reduces columns w, w+16, w+32; float4 batched loads.
__global__ __launch_bounds__(1024) void msiw_pass2(const float* __restrict__ ws,
                                                   float* __restrict__ out) {
    __shared__ float s_col[COLS];
    const int tid  = threadIdx.x;
    const int wv   = tid >> 6;       // 0..15
    const int lane = tid & 63;

    for (int col = wv; col < COLS; col += 16) {
        const float4* q = reinterpret_cast<const float4*>(ws + (size_t)col * CSTRIDE);
        float4 a[4];
        #pragma unroll
        for (int i = 0; i < 4; ++i) a[i] = q[lane + i * 64];   // 256 float4 = 1024 f
        float acc = 0.0f;
        #pragma unroll
        for (int i = 0; i < 4; ++i) acc += (a[i].x + a[i].y) + (a[i].z + a[i].w);
        #pragma unroll
        for (int off = 32; off > 0; off >>= 1) acc += __shfl_down(acc, off);
        if (lane == 0) s_col[col] = acc;
    }
    __syncthreads();

    if (tid == 0) {
        const double np_pow = pow((double)NN * HH * WW, 0.8);   // Np^(1-iw)
        double total = 0.0;
        for (int c = 0; c < NC; ++c) {
            double den = pow((double)s_col[NC + c], 0.2) * np_pow;
            if (den < 1.0) den = 1.0;
            total += (double)s_col[c] / den;
        }
        out[0] = (float)(-total / (double)(NN * NC));
    }
}

extern "C" void kernel_launch(void* const* d_in, const int* in_sizes, int n_in,
                              void* d_out, int out_size, void* d_ws, size_t ws_size,
                              hipStream_t stream) {
    const float* x = (const float*)d_in[0];
    float* ws = (float*)d_ws;                 // 38 cols * 1024 floats = 156 KB
    float* out = (float*)d_out;

    msiw_pass1<<<NBLK, 256, 0, stream>>>(x, ws);
    msiw_pass2<<<1, 1024, 0, stream>>>(ws, out);
}